// Round 6
// baseline (1050.605 us; speedup 1.0000x reference)
//
#include <hip/hip_runtime.h>

typedef unsigned short u16;
typedef unsigned int   u32;
typedef short bf16x8 __attribute__((ext_vector_type(8)));
typedef short bf16x4 __attribute__((ext_vector_type(4)));
typedef float f32x4  __attribute__((ext_vector_type(4)));

#define TT   131072         // B*N tokens
#define SCALE 0.17677669529663687f

__device__ __forceinline__ float bf2f(u32 u) {
    u32 v = u << 16;
    float f;
    __builtin_memcpy(&f, &v, 4);
    return f;
}
__device__ __forceinline__ u16 f2bf(float f) {
    u32 v;
    __builtin_memcpy(&v, &f, 4);
    u32 r = v + 0x7fffu + ((v >> 16) & 1u);
    return (u16)(r >> 16);
}

// pack two f32 -> one u32 of 2 bf16 (RNE) in a single instruction
__device__ __forceinline__ u32 cvtpk(float a, float b) {
    u32 r;
    asm("v_cvt_pk_bf16_f32 %0, %1, %2" : "=v"(r) : "v"(a), "v"(b));
    return r;
}

#if __has_builtin(__builtin_amdgcn_mfma_f32_16x16x16bf16_1k)
#define HAVE_MFMA16_BUILTIN 1
#endif

__device__ __forceinline__ f32x4 mfma16(bf16x4 a, bf16x4 b, f32x4 c) {
#ifdef HAVE_MFMA16_BUILTIN
    return __builtin_amdgcn_mfma_f32_16x16x16bf16_1k(a, b, c, 0, 0, 0);
#else
    asm volatile("v_mfma_f32_16x16x16_bf16 %0, %1, %2, %0"
                 : "+v"(c) : "v"(a), "v"(b));
    return c;
#endif
}

// async global->LDS, 16B per lane, dest = uniform base + lane*16
#define GLD16(g, l)                                                           \
    __builtin_amdgcn_global_load_lds(                                         \
        (const __attribute__((address_space(1))) void*)(g),                   \
        (__attribute__((address_space(3))) void*)(l), 16, 0, 0)

// ---------------- weight conversion + fragment-shuffle (once per launch) ----
// wbf element layout:
//   qkv_sh [0,196608)        shuffled fragment-order (Nc=768,K=256)
//   fc1_sh [196608,458752)   shuffled (Nc=1024,K=256)
//   fc2_sh [458752,720896)   shuffled (Nc=256,K=1024)
//   pjl    [720896,983040)   LINEAR rows c of [projw(256) | W'(768)]
//   zero16 [983040,983048)
// Fragment order: f = (cb*(K/32) + ks)*8 + nf; element = f*512 + l*8 + j
//   holds W[cb*128 + nf*16 + (l&15)][ks*32 + (l>>4)*8 + j]
__global__ __launch_bounds__(256) void cvt_kernel(
    const float* __restrict__ qkvw, const float* __restrict__ projw,
    const float* __restrict__ fc1w, const float* __restrict__ fc2w,
    u16* __restrict__ dst) {
    int i = blockIdx.x * 256 + threadIdx.x;
    if (i >= 983048) return;
    float v;
    if (i < 720896) {
        const float* W;
        int e, K, ksmask, cbshift;
        if (i < 196608)      { W = qkvw; e = i;          K = 256;  ksmask = 7;  cbshift = 6; }
        else if (i < 458752) { W = fc1w; e = i - 196608; K = 256;  ksmask = 7;  cbshift = 6; }
        else                 { W = fc2w; e = i - 458752; K = 1024; ksmask = 31; cbshift = 8; }
        int f = e >> 9, l = (e >> 3) & 63, j = e & 7;
        int nf = f & 7;
        int ks = (f >> 3) & ksmask;
        int cb = f >> cbshift;
        int row = cb * 128 + nf * 16 + (l & 15);
        int col = ks * 32 + ((l >> 4) << 3) + j;
        v = W[row * K + col];
    } else if (i < 983040) {
        int local = i - 720896;
        int kk = local & 1023;
        if (kk >= 256) return;          // W' part written by compose_kernel
        v = projw[(local >> 10) * 256 + kk];
    } else v = 0.0f;                    // zero16 block
    dst[i] = f2bf(v);
}

// ---- compose W'[c, tap*256+ci] = sum_j projw[c,j]*posw[j,ci,tap] (fp32) ----
// also bias2[c] = projb[c] + sum_j projw[c,j]*posb[j]
__global__ __launch_bounds__(256) void compose_kernel(
    const float* __restrict__ projw, const float* __restrict__ posw,
    const float* __restrict__ projb, const float* __restrict__ posb,
    u16* __restrict__ pjl, float* __restrict__ bias2) {
    int c = blockIdx.x, t = threadIdx.x;
    __shared__ float pr[256];
    pr[t] = projw[c * 256 + t];
    __syncthreads();
    #pragma unroll
    for (int r = 0; r < 3; ++r) {
        int kp = r * 256 + t;
        int tap = kp >> 8, ci = kp & 255;
        float acc = 0.f;
        for (int j = 0; j < 256; ++j)
            acc += pr[j] * posw[j * 768 + ci * 3 + tap];
        pjl[(size_t)c * 1024 + 256 + kp] = f2bf(acc);
    }
    float b = pr[t] * posb[t];
    #pragma unroll
    for (int o = 32; o > 0; o >>= 1) b += __shfl_down(b, o);
    __shared__ float pb4[4];
    if ((t & 63) == 0) pb4[t >> 6] = b;
    __syncthreads();
    if (t == 0) bias2[c] = projb[c] + pb4[0] + pb4[1] + pb4[2] + pb4[3];
}

// ---------------- LayerNorm (+optional intra-batch roll), fp32 in -> bf16 out
template <int SH>
__global__ __launch_bounds__(256) void ln_kernel(const float* __restrict__ x,
                                                 const float* __restrict__ w,
                                                 const float* __restrict__ bb,
                                                 u16* __restrict__ out) {
    int wid = threadIdx.x >> 6, lane = threadIdx.x & 63;
    int tl = blockIdx.x * 4 + wid;
    int src = (tl & ~4095) | ((tl + SH) & 4095);
    int c = lane * 4;
    float4 v = *(const float4*)(x + (size_t)src * 256 + c);
    float s1 = v.x + v.y + v.z + v.w;
    float s2 = v.x * v.x + v.y * v.y + v.z * v.z + v.w * v.w;
    #pragma unroll
    for (int o = 32; o > 0; o >>= 1) {
        s1 += __shfl_xor(s1, o);
        s2 += __shfl_xor(s2, o);
    }
    float mean = s1 * (1.0f / 256.0f);
    float rs = rsqrtf(s2 * (1.0f / 256.0f) - mean * mean + 1e-5f);
    float4 wv = *(const float4*)(w + c);
    float4 bv = *(const float4*)(bb + c);
    uint2 o2;
    o2.x = cvtpk((v.x - mean) * rs * wv.x + bv.x, (v.y - mean) * rs * wv.y + bv.y);
    o2.y = cvtpk((v.z - mean) * rs * wv.z + bv.z, (v.w - mean) * rs * wv.w + bv.w);
    *(uint2*)(out + (size_t)tl * 256 + c) = o2;
}

// ---------------- direct-B MFMA GEMM: C = A @ Wsh^T + bias ------------------
// 128x128 tile, BK=32, 4 waves (2x2 of 64x64). B operand comes DIRECTLY from
// global (pre-shuffled fragment-linear weights, fully coalesced 1KB loads,
// register-prefetched 1 step). A staged via global_load_lds into a TRIPLE
// buffer (24KB LDS) with counted vmcnt(6) and ONE raw s_barrier per K-step —
// loads stay in flight across barriers (T4). Halves LDS traffic vs the old
// engine (6KB/wave/step), which was the binding resource (~600 TF ceiling).
// MODE 0: Cb[r*Nc+c] = v;  MODE 3: Cf[r*256+c] = v + resf[r*256+c].
template <int MODE, int ACT>
__global__ __launch_bounds__(256, 4) void dgemm(
    const u16* __restrict__ A, const u16* __restrict__ Wsh,
    const float* __restrict__ bias, u16* __restrict__ Cb,
    float* __restrict__ Cf, const float* __restrict__ resf,
    int Nc, int K) {
    __shared__ u16 As[3][128 * 32];     // 24 KB
    const int tid = threadIdx.x;
    const int m0 = blockIdx.x * 128;
    const int w4 = tid >> 6, lane = tid & 63;
    const int srow = 32 * w4 + (lane >> 2);
    const int scol = (lane & 3) * 8;
    const u16* ag  = A + (size_t)(m0 + srow) * K + scol;
    const u16* ag2 = ag + (size_t)16 * K;
    const int frow = lane & 15, fk = (lane >> 4) * 8;
    const int am = (w4 & 1) * 64;
    const int bn16 = (w4 >> 1) * 4;     // nf base of this wave
    const int KS = K >> 5;
    const u16* wq = Wsh + ((size_t)blockIdx.y * KS * 8 + bn16) * 512 + lane * 8;
    const int lofs = w4 * 1024;

    f32x4 acc[4][4];
    #pragma unroll
    for (int i = 0; i < 4; ++i)
        #pragma unroll
        for (int j = 0; j < 4; ++j) acc[i][j] = (f32x4){0.f, 0.f, 0.f, 0.f};

    bf16x8 R0[4], R1[4];
    auto STAGE = [&](int b, int ks) {
        GLD16(ag  + ks * 32, &As[b][lofs]);
        GLD16(ag2 + ks * 32, &As[b][lofs + 512]);
    };
    auto LOADB = [&](bf16x8* R, int ks) {
        const u16* p = wq + (size_t)ks * 4096;
        #pragma unroll
        for (int ni = 0; ni < 4; ++ni) R[ni] = *(const bf16x8*)(p + ni * 512);
    };
    auto COMPUTE = [&](int b, bf16x8* R) {
        #pragma unroll
        for (int mi = 0; mi < 4; ++mi) {
            bf16x8 af = *(const bf16x8*)&As[b][(am + mi * 16 + frow) * 32 + fk];
            #pragma unroll
            for (int ni = 0; ni < 4; ++ni)
                acc[mi][ni] = __builtin_amdgcn_mfma_f32_16x16x32_bf16(
                    af, R[ni], acc[mi][ni], 0, 0, 0);
        }
    };

    // prologue: A staged 2 deep, B 1 deep
    STAGE(0, 0);
    STAGE(1, 1);
    LOADB(R0, 0);
    int bc = 0;                          // compute buffer for step t
    for (int t = 0; t + 2 < KS; t += 2) {
        asm volatile("s_waitcnt vmcnt(6)" ::: "memory");  // step-t A staged
        __builtin_amdgcn_s_barrier();
        int bs = bc + 2; if (bs >= 3) bs -= 3;
        STAGE(bs, t + 2);
        LOADB(R1, t + 1);
        COMPUTE(bc, R0);                 // compiler waits B(t) (counted)
        bc = bc + 1; if (bc >= 3) bc -= 3;

        asm volatile("s_waitcnt vmcnt(6)" ::: "memory");
        __builtin_amdgcn_s_barrier();
        if (t + 3 < KS) { int b2 = bc + 2; if (b2 >= 3) b2 -= 3; STAGE(b2, t + 3); }
        LOADB(R0, t + 2);
        COMPUTE(bc, R1);
        bc = bc + 1; if (bc >= 3) bc -= 3;
    }
    // tail: steps KS-2 (R0), KS-1 (R1); no further staging
    asm volatile("s_waitcnt vmcnt(6)" ::: "memory");
    __builtin_amdgcn_s_barrier();
    LOADB(R1, KS - 1);
    COMPUTE(bc, R0);
    bc = bc + 1; if (bc >= 3) bc -= 3;
    asm volatile("s_waitcnt vmcnt(4)" ::: "memory");      // last A buffer in
    __builtin_amdgcn_s_barrier();
    COMPUTE(bc, R1);

    // epilogue; C/D layout: col = lane&15, row = (lane>>4)*4 + reg
    const int n0 = blockIdx.y * 128;
    const int erow = am + ((lane >> 4) << 2);
    const int ecol = (w4 >> 1) * 64 + (lane & 15);
    #pragma unroll
    for (int ni = 0; ni < 4; ++ni) {
        int c = n0 + ecol + ni * 16;
        float bv = bias[c];
        #pragma unroll
        for (int mi = 0; mi < 4; ++mi) {
            #pragma unroll
            for (int reg = 0; reg < 4; ++reg) {
                int r = m0 + erow + mi * 16 + reg;
                float v = acc[mi][ni][reg] + bv;
                if (ACT == 1) v = 0.5f * v * (1.0f + erff(v * 0.70710678118654752f));
                if (MODE == 0) {
                    Cb[(size_t)r * Nc + c] = f2bf(v);
                } else {
                    Cf[(size_t)r * 256 + c] = v + resf[(size_t)r * 256 + c];
                }
            }
        }
    }
}

// ---------------- LDS-staged MFMA GEMM (kept for the fused proj+LePE) -------
// 128x128 tile, BK=32, 4 waves, double-buffered LDS, counted vmcnt(4).
// MODE 2: Cf[drl*256+c] = v + resf[drl*256+c]  (proj + reverse-roll + residual)
// AM 1: A-operand: K=1024, row t = [attn(256) | v(t-1) | v(t) | v(t+1)]
template <int MODE, int ACT, int AM>
__global__ __launch_bounds__(256) void mgemm(
    const u16* __restrict__ A, const u16* __restrict__ A2,
    const u16* __restrict__ W, const u16* __restrict__ Z,
    const float* __restrict__ bias, u16* __restrict__ Cb,
    float* __restrict__ Cf, const float* __restrict__ resf,
    int Nc, int K) {
    __shared__ u16 As[2][128 * 32];
    __shared__ u16 Bs[2][128 * 32];
    const int tid = threadIdx.x;
    const int m0 = blockIdx.x * 128, n0 = blockIdx.y * 128;
    const int w4 = tid >> 6, lane = tid & 63;
    const int srow = 32 * w4 + (lane >> 2);
    const int scol = (lane & 3) * 8;
    const u16* ag = (AM == 0) ? A + (size_t)(m0 + srow) * K + scol : A;
    const u16* bg = W + (size_t)(n0 + srow) * K + scol;
    const int lofs = w4 * 1024;
    const int frow = lane & 15, fk = (lane >> 4) * 8;
    const int am = (w4 & 1) * 64, bn = (w4 >> 1) * 64;

    const u16 *pA00, *pA10, *pA01, *pA11, *pA02, *pA12, *pA03, *pA13;
    if constexpr (AM == 1) {
        int t0 = m0 + srow, t1 = t0 + 16;
        int tq0 = t0 & 63, tq1 = t1 & 63;
        pA00 = A + (size_t)t0 * 256 + scol;
        pA10 = A + (size_t)t1 * 256 + scol;
        pA01 = (tq0 > 0)  ? A2 + (long)(t0 - 1) * 768 + 512 + scol : Z;
        pA11 = (tq1 > 0)  ? A2 + (long)(t1 - 1) * 768 + 512 + scol : Z;
        pA02 = A2 + (size_t)t0 * 768 + 512 + scol;
        pA12 = A2 + (size_t)t1 * 768 + 512 + scol;
        pA03 = (tq0 < 63) ? A2 + (long)(t0 + 1) * 768 + 512 + scol : Z;
        pA13 = (tq1 < 63) ? A2 + (long)(t1 + 1) * 768 + 512 + scol : Z;
    }

    f32x4 acc[4][4];
    #pragma unroll
    for (int i = 0; i < 4; ++i)
        #pragma unroll
        for (int j = 0; j < 4; ++j) acc[i][j] = (f32x4){0.f, 0.f, 0.f, 0.f};

    auto STAGE = [&](int b, int k0) {
        u16* lA = &As[b][lofs];
        u16* lB = &Bs[b][lofs];
        if constexpr (AM == 1) {
            int kl = k0 & 255;
            const u16 *p0, *p1;
            switch (k0 >> 8) {
                case 0:  p0 = pA00 + kl; p1 = pA10 + kl; break;
                case 1:  p0 = (pA01 == Z) ? Z : pA01 + kl;
                         p1 = (pA11 == Z) ? Z : pA11 + kl; break;
                case 2:  p0 = pA02 + kl; p1 = pA12 + kl; break;
                default: p0 = (pA03 == Z) ? Z : pA03 + kl;
                         p1 = (pA13 == Z) ? Z : pA13 + kl; break;
            }
            GLD16(p0, lA);
            GLD16(p1, lA + 512);
        } else {
            GLD16(ag + k0, lA);
            GLD16(ag + k0 + (size_t)16 * K, lA + 512);
        }
        GLD16(bg + k0, lB);
        GLD16(bg + (size_t)16 * K + k0, lB + 512);
    };
    auto COMPUTE = [&](int b) {
        bf16x8 af[4], bfr[4];
        #pragma unroll
        for (int mi = 0; mi < 4; ++mi)
            af[mi] = *(const bf16x8*)&As[b][(am + mi * 16 + frow) * 32 + fk];
        #pragma unroll
        for (int ni = 0; ni < 4; ++ni)
            bfr[ni] = *(const bf16x8*)&Bs[b][(bn + ni * 16 + frow) * 32 + fk];
        #pragma unroll
        for (int mi = 0; mi < 4; ++mi)
            #pragma unroll
            for (int ni = 0; ni < 4; ++ni)
                acc[mi][ni] = __builtin_amdgcn_mfma_f32_16x16x32_bf16(
                    af[mi], bfr[ni], acc[mi][ni], 0, 0, 0);
    };

    STAGE(0, 0);
    int cur = 0;
    const int nt = K >> 5;
    for (int t = 0; t < nt - 1; ++t) {
        STAGE(cur ^ 1, (t + 1) << 5);
        asm volatile("s_waitcnt vmcnt(4)" ::: "memory");
        __builtin_amdgcn_s_barrier();
        COMPUTE(cur);
        asm volatile("s_waitcnt lgkmcnt(0)" ::: "memory");
        __builtin_amdgcn_s_barrier();
        cur ^= 1;
    }
    asm volatile("s_waitcnt vmcnt(0)" ::: "memory");
    __builtin_amdgcn_s_barrier();
    COMPUTE(cur);

    const int erow = am + ((lane >> 4) << 2);
    const int ecol = bn + (lane & 15);
    #pragma unroll
    for (int ni = 0; ni < 4; ++ni) {
        int c = n0 + ecol + ni * 16;
        float bv = bias[c];
        #pragma unroll
        for (int mi = 0; mi < 4; ++mi) {
            #pragma unroll
            for (int reg = 0; reg < 4; ++reg) {
                int r = m0 + erow + mi * 16 + reg;
                float v = acc[mi][ni][reg] + bv;
                if (ACT == 1) v = 0.5f * v * (1.0f + erff(v * 0.70710678118654752f));
                if (MODE == 0) {
                    Cb[(size_t)r * Nc + c] = f2bf(v);
                } else if (MODE == 2) {
                    size_t drl = (size_t)((r & ~4095) | ((r + 32) & 4095));
                    Cf[drl * 256 + c] = v + resf[drl * 256 + c];
                } else {
                    Cf[(size_t)r * 256 + c] = v + resf[(size_t)r * 256 + c];
                }
            }
        }
    }
}

// ---------------- MFMA attention: one block per window, wave = 2 heads ------
__global__ __launch_bounds__(256) void attn_mfma(const u16* __restrict__ qkv,
                                                 const float* __restrict__ mask,
                                                 u16* __restrict__ outb) {
    __shared__ u16 Vt[8][32][68];
    __shared__ float Mt[64][68];
    __shared__ int mflag;

    const int w   = blockIdx.x;
    const int nw  = w & 63;
    const int tid = threadIdx.x;
    const int wid = tid >> 6, lane = tid & 63;
    const int g = lane >> 4, q15 = lane & 15;

    if (tid == 0) mflag = 0;
    __syncthreads();

    {
        const float* mrow = mask + (size_t)nw * 4096;
        int nz = 0;
        #pragma unroll
        for (int i = 0; i < 16; ++i) {
            int e = i * 256 + tid;
            float m = mrow[e];
            nz |= (m != 0.0f);
            Mt[e & 63][e >> 6] = m;
        }
        if (nz) mflag = 1;
    }

    {
        const u16* vg = qkv + (size_t)(w * 64) * 768 + 512;
        #pragma unroll
        for (int p = 0; p < 8; ++p) {
            int t  = lane;
            int c0 = wid * 8 + p * 32;
            uint4 u = *(const uint4*)(vg + (size_t)t * 768 + c0);
            u16 el[8];
            *(uint4*)el = u;
            int h = c0 >> 5, d0 = c0 & 31;
            #pragma unroll
            for (int j = 0; j < 8; ++j) Vt[h][d0 + j][t] = el[j];
        }
    }
    __syncthreads();

    const int hasmask = mflag;

    #pragma unroll
    for (int hh = 0; hh < 2; ++hh) {
        const int h = wid * 2 + hh;

        const u16* kbase = qkv + (size_t)(w * 64) * 768 + 256 + h * 32 + g * 8;
        const u16* qbase = qkv + (size_t)(w * 64) * 768 +       h * 32 + g * 8;
        bf16x8 kf[4], qf[4];
        #pragma unroll
        for (int mt = 0; mt < 4; ++mt)
            kf[mt] = *(const bf16x8*)(kbase + (size_t)(16 * mt + q15) * 768);
        #pragma unroll
        for (int nt = 0; nt < 4; ++nt)
            qf[nt] = *(const bf16x8*)(qbase + (size_t)(16 * nt + q15) * 768);

        f32x4 s[4][4];
        #pragma unroll
        for (int mt = 0; mt < 4; ++mt)
            #pragma unroll
            for (int nt = 0; nt < 4; ++nt) s[mt][nt] = (f32x4){0.f, 0.f, 0.f, 0.f};
        #pragma unroll
        for (int mt = 0; mt < 4; ++mt)
            #pragma unroll
            for (int nt = 0; nt < 4; ++nt)
                s[mt][nt] = __builtin_amdgcn_mfma_f32_16x16x32_bf16(
                    kf[mt], qf[nt], s[mt][nt], 0, 0, 0);

        if (hasmask) {
            #pragma unroll
            for (int mt = 0; mt < 4; ++mt)
                #pragma unroll
                for (int nt = 0; nt < 4; ++nt)
                    #pragma unroll
                    for (int r = 0; r < 4; ++r)
                        s[mt][nt][r] = s[mt][nt][r] * SCALE +
                                       Mt[16 * mt + 4 * g + r][16 * nt + q15];
        } else {
            #pragma unroll
            for (int mt = 0; mt < 4; ++mt)
                #pragma unroll
                for (int nt = 0; nt < 4; ++nt)
                    #pragma unroll
                    for (int r = 0; r < 4; ++r)
                        s[mt][nt][r] *= SCALE;
        }

        float inv[4];
        #pragma unroll
        for (int nt = 0; nt < 4; ++nt) {
            float mx = -3.0e38f;
            #pragma unroll
            for (int mt = 0; mt < 4; ++mt)
                #pragma unroll
                for (int r = 0; r < 4; ++r) mx = fmaxf(mx, s[mt][nt][r]);
            mx = fmaxf(mx, __shfl_xor(mx, 16));
            mx = fmaxf(mx, __shfl_xor(mx, 32));
            float sum = 0.f;
            #pragma unroll
            for (int mt = 0; mt < 4; ++mt)
                #pragma unroll
                for (int r = 0; r < 4; ++r) {
                    float p = __expf(s[mt][nt][r] - mx);
                    s[mt][nt][r] = p;
                    sum += p;
                }
            sum += __shfl_xor(sum, 16);
            sum += __shfl_xor(sum, 32);
            inv[nt] = 1.0f / sum;
        }

        bf16x4 pb[4][4];
        #pragma unroll
        for (int mt = 0; mt < 4; ++mt)
            #pragma unroll
            for (int nt = 0; nt < 4; ++nt) {
                u32 pk[2];
                pk[0] = cvtpk(s[mt][nt][0], s[mt][nt][1]);
                pk[1] = cvtpk(s[mt][nt][2], s[mt][nt][3]);
                bf16x4 bv;
                __builtin_memcpy(&bv, pk, 8);
                pb[mt][nt] = bv;
            }

        f32x4 o[2][4];
        #pragma unroll
        for (int ma = 0; ma < 2; ++ma)
            #pragma unroll
            for (int nt = 0; nt < 4; ++nt) o[ma][nt] = (f32x4){0.f, 0.f, 0.f, 0.f};
        #pragma unroll
        for (int kt = 0; kt < 4; ++kt) {
            bf16x4 a0 = *(const bf16x4*)&Vt[h][q15][16 * kt + 4 * g];
            bf16x4 a1 = *(const bf16x4*)&Vt[h][16 + q15][16 * kt + 4 * g];
            #pragma unroll
            for (int nt = 0; nt < 4; ++nt) {
                o[0][nt] = mfma16(a0, pb[kt][nt], o[0][nt]);
                o[1][nt] = mfma16(a1, pb[kt][nt], o[1][nt]);
            }
        }

        u16* ob = outb + (size_t)(w * 64) * 256 + h * 32;
        #pragma unroll
        for (int nt = 0; nt < 4; ++nt) {
            float iv = inv[nt];
            int tok = 16 * nt + q15;
            #pragma unroll
            for (int ma = 0; ma < 2; ++ma) {
                uint2 val;
                val.x = cvtpk(o[ma][nt][0] * iv, o[ma][nt][1] * iv);
                val.y = cvtpk(o[ma][nt][2] * iv, o[ma][nt][3] * iv);
                *(uint2*)(ob + (size_t)tok * 256 + 16 * ma + 4 * g) = val;
            }
        }
    }
}

extern "C" void kernel_launch(void* const* d_in, const int* in_sizes, int n_in,
                              void* d_out, int out_size, void* d_ws, size_t ws_size,
                              hipStream_t stream) {
    const float* x     = (const float*)d_in[0];
    const float* mask  = (const float*)d_in[1];
    const float* n1w   = (const float*)d_in[2];
    const float* n1b   = (const float*)d_in[3];
    const float* qkvw  = (const float*)d_in[4];
    const float* qkvbi = (const float*)d_in[5];
    const float* posw  = (const float*)d_in[6];
    const float* posb  = (const float*)d_in[7];
    const float* projw = (const float*)d_in[8];
    const float* projb = (const float*)d_in[9];
    const float* n2w   = (const float*)d_in[10];
    const float* n2b   = (const float*)d_in[11];
    const float* fc1w  = (const float*)d_in[12];
    const float* fc1b  = (const float*)d_in[13];
    const float* fc2w  = (const float*)d_in[14];
    const float* fc2b  = (const float*)d_in[15];

    int CB = 32;
    while (CB > 1 && (size_t)CB * 4096 * 4096 + 1967120ull > ws_size) CB >>= 1;
    const int TC = CB * 4096;

    char* ws = (char*)d_ws;
    u16*   hs   = (u16*)ws;
    u16*   attn = (u16*)(ws + (size_t)TC * 512);
    float* x1   = (float*)(ws + (size_t)TC * 1024);
    u16*   qkv  = (u16*)(ws + (size_t)TC * 2048);
    u16*   mid  = qkv;
    u16*   wbf  = (u16*)(ws + (size_t)TC * 4096);
    u16* qkv_sh = wbf;
    u16* fc1_sh = wbf + 196608;
    u16* fc2_sh = wbf + 458752;
    u16* pjl    = wbf + 720896;
    u16* zero16 = wbf + 983040;
    float* bias2 = (float*)((char*)wbf + 1966096);

    cvt_kernel<<<3841, 256, 0, stream>>>(qkvw, projw, fc1w, fc2w, wbf);
    compose_kernel<<<256, 256, 0, stream>>>(projw, posw, projb, posb, pjl, bias2);

    for (int t0 = 0; t0 < TT; t0 += TC) {
        const float* xc = x + (size_t)t0 * 256;
        // 1. LN1 + roll(-32)
        ln_kernel<32><<<TC / 4, 256, 0, stream>>>(xc, n1w, n1b, hs);
        // 2. QKV GEMM (direct-B engine)
        dgemm<0, 0><<<dim3(TC / 128, 6), 256, 0, stream>>>(
            hs, qkv_sh, qkvbi, qkv, nullptr, nullptr, 768, 256);
        // 3. windowed attention
        attn_mfma<<<TC / 64, 256, 0, stream>>>(qkv, mask, attn);
        // 4. fused (attn@proj^T + v_taps@(proj·posw)^T) + reverse-roll + residual
        mgemm<2, 0, 1><<<dim3(TC / 128, 2), 256, 0, stream>>>(
            attn, qkv, pjl, zero16, bias2, nullptr, x1, xc, 256, 1024);
        // 5. LN2
        ln_kernel<0><<<TC / 4, 256, 0, stream>>>(x1, n2w, n2b, hs);
        // 6. FC1 + exact GELU (direct-B engine)
        dgemm<0, 1><<<dim3(TC / 128, 8), 256, 0, stream>>>(
            hs, fc1_sh, fc1b, mid, nullptr, nullptr, 1024, 256);
        // 7. FC2 + residual -> d_out (direct-B engine)
        dgemm<3, 0><<<dim3(TC / 128, 2), 256, 0, stream>>>(
            mid, fc2_sh, fc2b, nullptr, (float*)d_out + (size_t)t0 * 256, x1,
            256, 1024);
    }
}